// Round 2
// baseline (766.272 us; speedup 1.0000x reference)
//
#include <hip/hip_runtime.h>
#include <stdint.h>

typedef unsigned short u16;
typedef __attribute__((ext_vector_type(8))) short short8;
typedef __attribute__((ext_vector_type(4))) float f32x4;

constexpr int SEQ   = 2048;
constexpr int HID   = 1024;
constexpr int NHEAD = 16;
constexpr int QKVD  = 1536;   // (16 + 2*4) * 64
constexpr int FFI   = 2816;
constexpr int NEXP  = 8;
constexpr int WINSZ = 512;
#define EPSF 1e-5f

__device__ __forceinline__ float bf2f(u16 u) {
  union { unsigned int i; float f; } v; v.i = ((unsigned int)u) << 16; return v.f;
}
__device__ __forceinline__ u16 f2bf(float f) {
  union { unsigned int i; float f; } v; v.f = f;
  unsigned int i = v.i;
  return (u16)((i + 0x7fffu + ((i >> 16) & 1u)) >> 16);
}

__device__ __forceinline__ void gload_lds16(const void* g, void* l) {
  __builtin_amdgcn_global_load_lds((__attribute__((address_space(1))) void*)g,
                                   (__attribute__((address_space(3))) void*)l,
                                   16, 0, 0);
}

#define MFMA_BF16(a, b, c) __builtin_amdgcn_mfma_f32_16x16x32_bf16(a, b, c, 0, 0, 0)

// ---------------- f32 -> bf16 weight conversion ----------------
__global__ __launch_bounds__(256) void k_f2b(const float* __restrict__ src,
                                             u16* __restrict__ dst, int n4) {
  int i = blockIdx.x * 256 + threadIdx.x;
  if (i < n4) {
    float4 v = ((const float4*)src)[i];
    ushort4 o;
    o.x = f2bf(v.x); o.y = f2bf(v.y); o.z = f2bf(v.z); o.w = f2bf(v.w);
    ((ushort4*)dst)[i] = o;
  }
}

// ---------------- RMSNorm (f32 in -> bf16 out) ----------------
__global__ __launch_bounds__(256) void k_rmsnorm(const float* __restrict__ x,
                                                 const float* __restrict__ w,
                                                 u16* __restrict__ y) {
  const int tkn = blockIdx.x, tid = threadIdx.x, wid = tid >> 6, lane = tid & 63;
  const float* xr = x + (size_t)tkn * HID;
  float4 v = *(const float4*)&xr[tid * 4];
  float ss = v.x * v.x + v.y * v.y + v.z * v.z + v.w * v.w;
#pragma unroll
  for (int m = 1; m < 64; m <<= 1) ss += __shfl_xor(ss, m);
  __shared__ float red[4];
  if (lane == 0) red[wid] = ss;
  __syncthreads();
  ss = red[0] + red[1] + red[2] + red[3];
  float sc = rsqrtf(ss * (1.0f / HID) + EPSF);
  float4 wv = *(const float4*)&w[tid * 4];
  ushort4 o;
  o.x = f2bf(v.x * sc * wv.x);
  o.y = f2bf(v.y * sc * wv.y);
  o.z = f2bf(v.z * sc * wv.z);
  o.w = f2bf(v.w * sc * wv.w);
  *(ushort4*)&y[(size_t)tkn * HID + tid * 4] = o;
}

// ---------------- generic C = A * B^T GEMM (m97 structure) ----------------
// MODE 0: bf16 C store. MODE 1: x2 = acc + resid(f32), store f32 only.
template <int MODE>
__global__ __launch_bounds__(256, 2) void k_gemm_bt(
    const u16* __restrict__ A, const u16* __restrict__ B, u16* __restrict__ C,
    int M, int N, int K, const float* __restrict__ resid, float* __restrict__ x2f) {
  __shared__ u16 As[128 * 64];
  __shared__ u16 Bs[128 * 64];
  const int tid = threadIdx.x, wid = tid >> 6, lane = tid & 63;
  const int quad = lane >> 4, l16 = lane & 15;
  const int wr = wid >> 1, wc = wid & 1;
  const int m0 = blockIdx.y * 128, n0 = blockIdx.x * 128;
  const int sr = lane >> 3, sc = (lane & 7) * 8;
  f32x4 acc[4][4] = {};
  const int KT = K >> 6;
  for (int kt = 0; kt < KT; ++kt) {
    const int k0 = kt << 6;
#pragma unroll
    for (int it = 0; it < 4; ++it) {
      int seg = wid * 4 + it;
      int row = seg * 8 + sr;
      gload_lds16(&A[(size_t)(m0 + row) * K + k0 + sc], &As[seg * 512]);
      gload_lds16(&B[(size_t)(n0 + row) * K + k0 + sc], &Bs[seg * 512]);
    }
    __syncthreads();
#pragma unroll
    for (int ks = 0; ks < 2; ++ks) {
      short8 af[4], bf[4];
#pragma unroll
      for (int t = 0; t < 4; ++t)
        af[t] = *(const short8*)&As[(64 * wr + 16 * t + l16) * 64 + ks * 32 + quad * 8];
#pragma unroll
      for (int t = 0; t < 4; ++t)
        bf[t] = *(const short8*)&Bs[(64 * wc + 16 * t + l16) * 64 + ks * 32 + quad * 8];
#pragma unroll
      for (int mt = 0; mt < 4; ++mt)
#pragma unroll
        for (int nt = 0; nt < 4; ++nt)
          acc[mt][nt] = MFMA_BF16(af[mt], bf[nt], acc[mt][nt]);
    }
    __syncthreads();
  }
#pragma unroll
  for (int mt = 0; mt < 4; ++mt)
#pragma unroll
    for (int r = 0; r < 4; ++r) {
      int row = m0 + 64 * wr + 16 * mt + quad * 4 + r;
#pragma unroll
      for (int nt = 0; nt < 4; ++nt) {
        int col = n0 + 64 * wc + 16 * nt + l16;
        float v = acc[mt][nt][r];
        if (MODE == 1) {
          x2f[(size_t)row * N + col] = v + resid[(size_t)row * N + col];
        } else {
          C[(size_t)row * N + col] = f2bf(v);
        }
      }
    }
}

// ---------------- sliding-window GQA flash attention ----------------
__global__ __launch_bounds__(256, 2) void k_attn(const u16* __restrict__ qkv,
                                                 u16* __restrict__ o) {
  const int qb = blockIdx.x;   // 0..31
  const int h = blockIdx.y;    // 0..15
  const int q0 = qb * 64;
  const int g = h >> 2;        // kv head
  __shared__ u16 Qs[64 * 72], Ks[64 * 72], Vt[64 * 72], Ps[64 * 72];
  const int tid = threadIdx.x, wid = tid >> 6, lane = tid & 63;
  const int quad = lane >> 4, l16 = lane & 15;

#pragma unroll
  for (int it = 0; it < 2; ++it) {
    int idx = it * 256 + tid;
    int row = idx >> 3, c8 = (idx & 7) * 8;
    *(short8*)&Qs[row * 72 + c8] =
        *(const short8*)&qkv[(size_t)(q0 + row) * QKVD + h * 64 + c8];
  }

  f32x4 oacc[4] = {};
  float mrun[4], lrun[4];
#pragma unroll
  for (int r = 0; r < 4; ++r) { mrun[r] = -1e30f; lrun[r] = 0.f; }

  const int ktlo = (q0 >= WINSZ) ? ((q0 - WINSZ + 1) >> 6) : 0;
  const int kthi = qb;
  for (int kt = ktlo; kt <= kthi; ++kt) {
#pragma unroll
    for (int it = 0; it < 2; ++it) {
      int idx = it * 256 + tid;
      int row = idx >> 3, c8 = (idx & 7) * 8;
      *(short8*)&Ks[row * 72 + c8] =
          *(const short8*)&qkv[(size_t)(kt * 64 + row) * QKVD + 1024 + g * 64 + c8];
    }
#pragma unroll
    for (int it = 0; it < 8; ++it) {
      int idx = it * 256 + tid;
      int key = idx >> 5;
      int d = (idx & 31) * 2;
      unsigned int u = *(const unsigned int*)&qkv[(size_t)(kt * 64 + key) * QKVD + 1280 + g * 64 + d];
      Vt[d * 72 + key] = (u16)(u & 0xffffu);
      Vt[(d + 1) * 72 + key] = (u16)(u >> 16);
    }
    __syncthreads();

    f32x4 sa[4] = {};
#pragma unroll
    for (int ks = 0; ks < 2; ++ks) {
      short8 af = *(const short8*)&Qs[(16 * wid + l16) * 72 + ks * 32 + quad * 8];
#pragma unroll
      for (int ct = 0; ct < 4; ++ct) {
        short8 bf = *(const short8*)&Ks[(16 * ct + l16) * 72 + ks * 32 + quad * 8];
        sa[ct] = MFMA_BF16(af, bf, sa[ct]);
      }
    }

    float pvv[4][4];
#pragma unroll
    for (int r = 0; r < 4; ++r) {
      int i = q0 + 16 * wid + quad * 4 + r;
      float mx = -1e30f;
#pragma unroll
      for (int ct = 0; ct < 4; ++ct) {
        int j = kt * 64 + 16 * ct + l16;
        float v = sa[ct][r] * 0.125f;
        bool ok = (j <= i) && (i - j < WINSZ);
        v = ok ? v : -1e30f;
        pvv[ct][r] = v;
        mx = fmaxf(mx, v);
      }
#pragma unroll
      for (int m = 1; m < 16; m <<= 1) mx = fmaxf(mx, __shfl_xor(mx, m));
      float mnew = fmaxf(mrun[r], mx);
      float alpha = __expf(mrun[r] - mnew);
      float s = 0.f;
#pragma unroll
      for (int ct = 0; ct < 4; ++ct) {
        float p = (pvv[ct][r] > -1e29f) ? __expf(pvv[ct][r] - mnew) : 0.f;
        pvv[ct][r] = p;
        s += p;
      }
#pragma unroll
      for (int m = 1; m < 16; m <<= 1) s += __shfl_xor(s, m);
      lrun[r] = lrun[r] * alpha + s;
      mrun[r] = mnew;
#pragma unroll
      for (int ct = 0; ct < 4; ++ct) oacc[ct][r] *= alpha;
    }
#pragma unroll
    for (int ct = 0; ct < 4; ++ct)
#pragma unroll
      for (int r = 0; r < 4; ++r)
        Ps[(16 * wid + quad * 4 + r) * 72 + 16 * ct + l16] = f2bf(pvv[ct][r]);
    __syncthreads();

#pragma unroll
    for (int ks = 0; ks < 2; ++ks) {
      short8 af = *(const short8*)&Ps[(16 * wid + l16) * 72 + ks * 32 + quad * 8];
#pragma unroll
      for (int ct = 0; ct < 4; ++ct) {
        short8 bf = *(const short8*)&Vt[(16 * ct + l16) * 72 + ks * 32 + quad * 8];
        oacc[ct] = MFMA_BF16(af, bf, oacc[ct]);
      }
    }
    __syncthreads();
  }

#pragma unroll
  for (int ct = 0; ct < 4; ++ct)
#pragma unroll
    for (int r = 0; r < 4; ++r) {
      int row = q0 + 16 * wid + quad * 4 + r;
      float v = oacc[ct][r] / lrun[r];
      o[(size_t)row * HID + h * 64 + 16 * ct + l16] = f2bf(v);
    }
}

// ---------------- RMSNorm2 (f32 in) + router top-2 ----------------
__global__ __launch_bounds__(256) void k_rms2_router(
    const float* __restrict__ x2f, const float* __restrict__ ln2,
    const float* __restrict__ rw, u16* __restrict__ T, int* __restrict__ counts,
    int* __restrict__ tok_idx, float* __restrict__ tok_w) {
  const int tkn = blockIdx.x, tid = threadIdx.x, wid = tid >> 6, lane = tid & 63;
  const float* xr = x2f + (size_t)tkn * HID;
  float4 v = *(const float4*)&xr[tid * 4];
  float ss = v.x * v.x + v.y * v.y + v.z * v.z + v.w * v.w;
#pragma unroll
  for (int m = 1; m < 64; m <<= 1) ss += __shfl_xor(ss, m);
  __shared__ float red[4];
  if (lane == 0) red[wid] = ss;
  __syncthreads();
  ss = red[0] + red[1] + red[2] + red[3];
  float sc = rsqrtf(ss * (1.0f / HID) + EPSF);
  float4 lw = *(const float4*)&ln2[tid * 4];
  float t0 = v.x * sc * lw.x;
  float t1 = v.y * sc * lw.y;
  float t2 = v.z * sc * lw.z;
  float t3 = v.w * sc * lw.w;
  ushort4 o;
  o.x = f2bf(t0); o.y = f2bf(t1); o.z = f2bf(t2); o.w = f2bf(t3);
  *(ushort4*)&T[(size_t)tkn * HID + tid * 4] = o;

  float p[8];
#pragma unroll
  for (int e = 0; e < 8; ++e) {
    float4 r = *(const float4*)&rw[e * HID + tid * 4];
    p[e] = t0 * r.x + t1 * r.y + t2 * r.z + t3 * r.w;
  }
#pragma unroll
  for (int e = 0; e < 8; ++e)
#pragma unroll
    for (int m = 1; m < 64; m <<= 1) p[e] += __shfl_xor(p[e], m);
  __shared__ float pr[4][8];
  if (lane == 0)
#pragma unroll
    for (int e = 0; e < 8; ++e) pr[wid][e] = p[e];
  __syncthreads();
  if (tid == 0) {
    float lg[8];
#pragma unroll
    for (int e = 0; e < 8; ++e) lg[e] = pr[0][e] + pr[1][e] + pr[2][e] + pr[3][e];
    float mx = lg[0];
#pragma unroll
    for (int e = 1; e < 8; ++e) mx = fmaxf(mx, lg[e]);
    float ex[8], se = 0.f;
#pragma unroll
    for (int e = 0; e < 8; ++e) { ex[e] = __expf(lg[e] - mx); se += ex[e]; }
    int b0 = 0;
#pragma unroll
    for (int e = 1; e < 8; ++e) if (lg[e] > lg[b0]) b0 = e;
    int b1 = (b0 == 0) ? 1 : 0;
#pragma unroll
    for (int e = 0; e < 8; ++e) if (e != b0 && lg[e] > lg[b1]) b1 = e;
    float inv = 1.0f / se;
    int s0 = atomicAdd(&counts[b0], 1);
    tok_idx[b0 * SEQ + s0] = tkn;
    tok_w[b0 * SEQ + s0] = ex[b0] * inv;
    int s1 = atomicAdd(&counts[b1], 1);
    tok_idx[b1 * SEQ + s1] = tkn;
    tok_w[b1 * SEQ + s1] = ex[b1] * inv;
  }
}

__global__ void k_offsets(const int* __restrict__ counts, int* __restrict__ offs) {
  if (threadIdx.x == 0 && blockIdx.x == 0) {
    int s = 0;
    for (int e = 0; e < NEXP; ++e) { offs[e] = s; s += counts[e]; }
    offs[NEXP] = s;
  }
}

// ---------------- MoE up GEMM (gathered A) + fused SiLU*u ----------------
__global__ __launch_bounds__(256, 2) void k_moe_gu(
    const u16* __restrict__ T, const u16* __restrict__ Wgu,
    const int* __restrict__ counts, const int* __restrict__ offs,
    const int* __restrict__ tok_idx, u16* __restrict__ Abuf) {
  const int e = blockIdx.z;
  const int cnt = counts[e];
  const int m0 = blockIdx.y * 128;
  if (m0 >= cnt) return;
  const int n0 = blockIdx.x * 128;
  const u16* We = Wgu + (size_t)e * 2 * FFI * HID;
  const int* ti = tok_idx + e * SEQ;
  const int aoff = offs[e];
  __shared__ u16 As[128 * 64], Bg[128 * 64], Bu[128 * 64];
  const int tid = threadIdx.x, wid = tid >> 6, lane = tid & 63;
  const int quad = lane >> 4, l16 = lane & 15;
  const int wr = wid >> 1, wc = wid & 1;
  const int sr = lane >> 3, sc = (lane & 7) * 8;
  int tokrow[4];
#pragma unroll
  for (int it = 0; it < 4; ++it) {
    int row = (wid * 4 + it) * 8 + sr;
    int ra = m0 + row;
    if (ra > cnt - 1) ra = cnt - 1;
    tokrow[it] = ti[ra];
  }
  f32x4 accg[4][4] = {}, accu[4][4] = {};
  for (int kt = 0; kt < 16; ++kt) {
    const int k0 = kt << 6;
#pragma unroll
    for (int it = 0; it < 4; ++it) {
      int seg = wid * 4 + it;
      int row = seg * 8 + sr;
      gload_lds16(&T[(size_t)tokrow[it] * HID + k0 + sc], &As[seg * 512]);
      gload_lds16(&We[(size_t)(n0 + row) * HID + k0 + sc], &Bg[seg * 512]);
      gload_lds16(&We[(size_t)(FFI + n0 + row) * HID + k0 + sc], &Bu[seg * 512]);
    }
    __syncthreads();
#pragma unroll
    for (int ks = 0; ks < 2; ++ks) {
      short8 af[4], bg[4], bu[4];
#pragma unroll
      for (int t = 0; t < 4; ++t)
        af[t] = *(const short8*)&As[(64 * wr + 16 * t + l16) * 64 + ks * 32 + quad * 8];
#pragma unroll
      for (int t = 0; t < 4; ++t)
        bg[t] = *(const short8*)&Bg[(64 * wc + 16 * t + l16) * 64 + ks * 32 + quad * 8];
#pragma unroll
      for (int t = 0; t < 4; ++t)
        bu[t] = *(const short8*)&Bu[(64 * wc + 16 * t + l16) * 64 + ks * 32 + quad * 8];
#pragma unroll
      for (int mt = 0; mt < 4; ++mt)
#pragma unroll
        for (int nt = 0; nt < 4; ++nt) {
          accg[mt][nt] = MFMA_BF16(af[mt], bg[nt], accg[mt][nt]);
          accu[mt][nt] = MFMA_BF16(af[mt], bu[nt], accu[mt][nt]);
        }
    }
    __syncthreads();
  }
#pragma unroll
  for (int mt = 0; mt < 4; ++mt)
#pragma unroll
    for (int r = 0; r < 4; ++r) {
      int rl = 64 * wr + 16 * mt + quad * 4 + r;
      int grow = m0 + rl;
      if (grow < cnt) {
        size_t rbase = (size_t)(aoff + grow) * FFI;
#pragma unroll
        for (int nt = 0; nt < 4; ++nt) {
          int col = n0 + 64 * wc + 16 * nt + l16;
          float gv = accg[mt][nt][r];
          float uv = accu[mt][nt][r];
          float a = gv / (1.0f + __expf(-gv)) * uv;
          Abuf[rbase + col] = f2bf(a);
        }
      }
    }
}

// ---------------- MoE down GEMM + weighted atomic scatter (f32 out) ----------------
__global__ __launch_bounds__(256, 2) void k_moe_y(
    const u16* __restrict__ Abuf, const u16* __restrict__ W2,
    const int* __restrict__ counts, const int* __restrict__ offs,
    const int* __restrict__ tok_idx, const float* __restrict__ tok_w,
    float* __restrict__ outf) {
  const int e = blockIdx.z;
  const int cnt = counts[e];
  const int m0 = blockIdx.y * 128;
  if (m0 >= cnt) return;
  const int n0 = blockIdx.x * 128;
  const u16* We = W2 + (size_t)e * HID * FFI;
  const int aoff = offs[e];
  __shared__ u16 As[128 * 64], Bs[128 * 64];
  const int tid = threadIdx.x, wid = tid >> 6, lane = tid & 63;
  const int quad = lane >> 4, l16 = lane & 15;
  const int wr = wid >> 1, wc = wid & 1;
  const int sr = lane >> 3, sc = (lane & 7) * 8;
  int arow[4];
#pragma unroll
  for (int it = 0; it < 4; ++it) {
    int row = (wid * 4 + it) * 8 + sr;
    int ra = m0 + row;
    if (ra > cnt - 1) ra = cnt - 1;
    arow[it] = aoff + ra;
  }
  f32x4 acc[4][4] = {};
  for (int kt = 0; kt < FFI / 64; ++kt) {
    const int k0 = kt << 6;
#pragma unroll
    for (int it = 0; it < 4; ++it) {
      int seg = wid * 4 + it;
      int row = seg * 8 + sr;
      gload_lds16(&Abuf[(size_t)arow[it] * FFI + k0 + sc], &As[seg * 512]);
      gload_lds16(&We[(size_t)(n0 + row) * FFI + k0 + sc], &Bs[seg * 512]);
    }
    __syncthreads();
#pragma unroll
    for (int ks = 0; ks < 2; ++ks) {
      short8 af[4], bf[4];
#pragma unroll
      for (int t = 0; t < 4; ++t)
        af[t] = *(const short8*)&As[(64 * wr + 16 * t + l16) * 64 + ks * 32 + quad * 8];
#pragma unroll
      for (int t = 0; t < 4; ++t)
        bf[t] = *(const short8*)&Bs[(64 * wc + 16 * t + l16) * 64 + ks * 32 + quad * 8];
#pragma unroll
      for (int mt = 0; mt < 4; ++mt)
#pragma unroll
        for (int nt = 0; nt < 4; ++nt)
          acc[mt][nt] = MFMA_BF16(af[mt], bf[nt], acc[mt][nt]);
    }
    __syncthreads();
  }
#pragma unroll
  for (int mt = 0; mt < 4; ++mt)
#pragma unroll
    for (int r = 0; r < 4; ++r) {
      int rl = 64 * wr + 16 * mt + quad * 4 + r;
      int grow = m0 + rl;
      if (grow < cnt) {
        int tok = tok_idx[e * SEQ + grow];
        float wgt = tok_w[e * SEQ + grow];
        size_t obase = (size_t)tok * HID;
#pragma unroll
        for (int nt = 0; nt < 4; ++nt) {
          int col = n0 + 64 * wc + 16 * nt + l16;
          atomicAdd(&outf[obase + col], wgt * acc[mt][nt][r]);
        }
      }
    }
}

extern "C" void kernel_launch(void* const* d_in, const int* in_sizes, int n_in,
                              void* d_out, int out_size, void* d_ws, size_t ws_size,
                              hipStream_t stream) {
  const float* hs   = (const float*)d_in[0];
  const float* wqkv = (const float*)d_in[2];
  const float* wo   = (const float*)d_in[3];
  const float* rwt  = (const float*)d_in[4];
  const float* wsx  = (const float*)d_in[5];
  const float* w2s  = (const float*)d_in[6];
  const float* ln1  = (const float*)d_in[7];
  const float* ln2  = (const float*)d_in[8];
  float* out0 = (float*)d_out;                       // MoE output (f32)
  float* out1 = out0 + (size_t)SEQ * HID;            // residual2 (f32)

  char* p = (char*)d_ws;
  u16* xn      = (u16*)p;   p += (size_t)SEQ * HID * 2;
  u16* qkv     = (u16*)p;   p += (size_t)SEQ * QKVD * 2;
  u16* ob      = (u16*)p;   p += (size_t)SEQ * HID * 2;
  u16* tb      = (u16*)p;   p += (size_t)SEQ * HID * 2;
  int* counts  = (int*)p;   p += 32;
  int* offs    = (int*)p;   p += 64;
  int* tok_idx = (int*)p;   p += (size_t)NEXP * SEQ * 4;
  float* tok_w = (float*)p; p += (size_t)NEXP * SEQ * 4;
  u16* abuf    = (u16*)p;   p += (size_t)2 * SEQ * FFI * 2;
  u16* wqkv_b  = (u16*)p;   p += (size_t)QKVD * HID * 2;
  u16* wo_b    = (u16*)p;   p += (size_t)HID * HID * 2;
  u16* ws_b    = (u16*)p;   p += (size_t)NEXP * 2 * FFI * HID * 2;
  u16* w2s_b   = (u16*)p;   p += (size_t)NEXP * HID * FFI * 2;

  hipMemsetAsync(counts, 0, 32, stream);
  hipMemsetAsync(out0, 0, (size_t)SEQ * HID * 4, stream);

  // weight f32 -> bf16 conversions
  {
    int n4;
    n4 = QKVD * HID / 4;
    k_f2b<<<(n4 + 255) / 256, 256, 0, stream>>>(wqkv, wqkv_b, n4);
    n4 = HID * HID / 4;
    k_f2b<<<(n4 + 255) / 256, 256, 0, stream>>>(wo, wo_b, n4);
    n4 = NEXP * 2 * FFI * HID / 4;
    k_f2b<<<(n4 + 255) / 256, 256, 0, stream>>>(wsx, ws_b, n4);
    n4 = NEXP * HID * FFI / 4;
    k_f2b<<<(n4 + 255) / 256, 256, 0, stream>>>(w2s, w2s_b, n4);
  }

  k_rmsnorm<<<SEQ, 256, 0, stream>>>(hs, ln1, xn);
  k_gemm_bt<0><<<dim3(QKVD / 128, SEQ / 128), 256, 0, stream>>>(
      xn, wqkv_b, qkv, SEQ, QKVD, HID, nullptr, nullptr);
  k_attn<<<dim3(SEQ / 64, NHEAD), 256, 0, stream>>>(qkv, ob);
  k_gemm_bt<1><<<dim3(HID / 128, SEQ / 128), 256, 0, stream>>>(
      ob, wo_b, nullptr, SEQ, HID, HID, hs, out1);
  k_rms2_router<<<SEQ, 256, 0, stream>>>(out1, ln2, rwt, tb, counts, tok_idx, tok_w);
  k_offsets<<<1, 64, 0, stream>>>(counts, offs);
  k_moe_gu<<<dim3(FFI / 128, SEQ / 128, NEXP), 256, 0, stream>>>(
      tb, ws_b, counts, offs, tok_idx, abuf);
  k_moe_y<<<dim3(HID / 128, SEQ / 128, NEXP), 256, 0, stream>>>(
      abuf, w2s_b, counts, offs, tok_idx, tok_w, out0);
}

// Round 3
// 661.350 us; speedup vs baseline: 1.1586x; 1.1586x over previous
//
#include <hip/hip_runtime.h>
#include <stdint.h>

typedef unsigned short u16;
typedef __attribute__((ext_vector_type(8))) short short8;
typedef __attribute__((ext_vector_type(4))) float f32x4;

constexpr int SEQ   = 2048;
constexpr int HID   = 1024;
constexpr int NHEAD = 16;
constexpr int QKVD  = 1536;   // (16 + 2*4) * 64
constexpr int FFI   = 2816;
constexpr int NEXP  = 8;
constexpr int WINSZ = 512;
#define EPSF 1e-5f

__device__ __forceinline__ float bf2f(u16 u) {
  union { unsigned int i; float f; } v; v.i = ((unsigned int)u) << 16; return v.f;
}
__device__ __forceinline__ u16 f2bf(float f) {
  union { unsigned int i; float f; } v; v.f = f;
  unsigned int i = v.i;
  return (u16)((i + 0x7fffu + ((i >> 16) & 1u)) >> 16);
}

__device__ __forceinline__ void gload_lds16(const void* g, void* l) {
  __builtin_amdgcn_global_load_lds((__attribute__((address_space(1))) void*)g,
                                   (__attribute__((address_space(3))) void*)l,
                                   16, 0, 0);
}

#define MFMA_BF16(a, b, c) __builtin_amdgcn_mfma_f32_16x16x32_bf16(a, b, c, 0, 0, 0)

// ---------------- fused f32 -> bf16 weight conversion (all 4 weights) ----
constexpr int CN1 = QKVD * HID / 4;            // 393216
constexpr int CN2 = HID * HID / 4;             // 262144
constexpr int CN3 = NEXP * 2 * FFI * HID / 4;  // 11534336
constexpr int CN4 = NEXP * HID * FFI / 4;      // 5767168
constexpr int CNT_ALL = CN1 + CN2 + CN3 + CN4; // 17956864

__global__ __launch_bounds__(256) void k_f2b_all(
    const float* __restrict__ wqkv, const float* __restrict__ wo,
    const float* __restrict__ ws, const float* __restrict__ w2s,
    u16* __restrict__ dq, u16* __restrict__ dwo,
    u16* __restrict__ dws, u16* __restrict__ dw2) {
  int i = blockIdx.x * 256 + threadIdx.x;
  if (i >= CNT_ALL) return;
  const float* s; u16* d; int j = i;
  if (j < CN1) { s = wqkv; d = dq; }
  else if ((j -= CN1) < CN2) { s = wo; d = dwo; }
  else if ((j -= CN2) < CN3) { s = ws; d = dws; }
  else { j -= CN3; s = w2s; d = dw2; }
  float4 v = ((const float4*)s)[j];
  ushort4 o;
  o.x = f2bf(v.x); o.y = f2bf(v.y); o.z = f2bf(v.z); o.w = f2bf(v.w);
  ((ushort4*)d)[j] = o;
}

// ---------------- RMSNorm (f32 in -> bf16 out) ----------------
__global__ __launch_bounds__(256) void k_rmsnorm(const float* __restrict__ x,
                                                 const float* __restrict__ w,
                                                 u16* __restrict__ y) {
  const int tkn = blockIdx.x, tid = threadIdx.x, wid = tid >> 6, lane = tid & 63;
  const float* xr = x + (size_t)tkn * HID;
  float4 v = *(const float4*)&xr[tid * 4];
  float ss = v.x * v.x + v.y * v.y + v.z * v.z + v.w * v.w;
#pragma unroll
  for (int m = 1; m < 64; m <<= 1) ss += __shfl_xor(ss, m);
  __shared__ float red[4];
  if (lane == 0) red[wid] = ss;
  __syncthreads();
  ss = red[0] + red[1] + red[2] + red[3];
  float sc = rsqrtf(ss * (1.0f / HID) + EPSF);
  float4 wv = *(const float4*)&w[tid * 4];
  ushort4 o;
  o.x = f2bf(v.x * sc * wv.x);
  o.y = f2bf(v.y * sc * wv.y);
  o.z = f2bf(v.z * sc * wv.z);
  o.w = f2bf(v.w * sc * wv.w);
  *(ushort4*)&y[(size_t)tkn * HID + tid * 4] = o;
}

// ------------- split-K C = A * B^T GEMM, f32 partial out per split -------
// grid: (N/128, M/128, nsplit). Cf[split][M][N].
__global__ __launch_bounds__(256, 2) void k_gemm_bt_sk(
    const u16* __restrict__ A, const u16* __restrict__ B, float* __restrict__ Cf,
    int N, int K, int Kc) {
  __shared__ u16 As[128 * 64];
  __shared__ u16 Bs[128 * 64];
  const int tid = threadIdx.x, wid = tid >> 6, lane = tid & 63;
  const int quad = lane >> 4, l16 = lane & 15;
  const int wr = wid >> 1, wc = wid & 1;
  const int m0 = blockIdx.y * 128, n0 = blockIdx.x * 128;
  const int M = gridDim.y * 128;
  const int kbase = blockIdx.z * Kc;
  const int sr = lane >> 3, sc = (lane & 7) * 8;
  f32x4 acc[4][4] = {};
  const int KT = Kc >> 6;
  for (int kt = 0; kt < KT; ++kt) {
    const int k0 = kbase + (kt << 6);
#pragma unroll
    for (int it = 0; it < 4; ++it) {
      int seg = wid * 4 + it;
      int row = seg * 8 + sr;
      gload_lds16(&A[(size_t)(m0 + row) * K + k0 + sc], &As[seg * 512]);
      gload_lds16(&B[(size_t)(n0 + row) * K + k0 + sc], &Bs[seg * 512]);
    }
    __syncthreads();
#pragma unroll
    for (int ks = 0; ks < 2; ++ks) {
      short8 af[4], bf[4];
#pragma unroll
      for (int t = 0; t < 4; ++t)
        af[t] = *(const short8*)&As[(64 * wr + 16 * t + l16) * 64 + ks * 32 + quad * 8];
#pragma unroll
      for (int t = 0; t < 4; ++t)
        bf[t] = *(const short8*)&Bs[(64 * wc + 16 * t + l16) * 64 + ks * 32 + quad * 8];
#pragma unroll
      for (int mt = 0; mt < 4; ++mt)
#pragma unroll
        for (int nt = 0; nt < 4; ++nt)
          acc[mt][nt] = MFMA_BF16(af[mt], bf[nt], acc[mt][nt]);
    }
    __syncthreads();
  }
  float* Co = Cf + (size_t)blockIdx.z * M * N;
#pragma unroll
  for (int mt = 0; mt < 4; ++mt)
#pragma unroll
    for (int r = 0; r < 4; ++r) {
      int row = m0 + 64 * wr + 16 * mt + quad * 4 + r;
#pragma unroll
      for (int nt = 0; nt < 4; ++nt) {
        int col = n0 + 64 * wc + 16 * nt + l16;
        Co[(size_t)row * N + col] = acc[mt][nt][r];
      }
    }
}

// ---------------- sum 2 split halves -> bf16 ----------------
__global__ __launch_bounds__(256) void k_sum2_bf16(const float* __restrict__ a,
                                                   const float* __restrict__ b,
                                                   u16* __restrict__ o, int n4) {
  int i = blockIdx.x * 256 + threadIdx.x;
  if (i >= n4) return;
  float4 x = ((const float4*)a)[i];
  float4 y = ((const float4*)b)[i];
  ushort4 u;
  u.x = f2bf(x.x + y.x); u.y = f2bf(x.y + y.y);
  u.z = f2bf(x.z + y.z); u.w = f2bf(x.w + y.w);
  ((ushort4*)o)[i] = u;
}

// ---------------- sliding-window GQA flash attention ----------------
__global__ __launch_bounds__(256, 2) void k_attn(const u16* __restrict__ qkv,
                                                 u16* __restrict__ o) {
  const int qb = blockIdx.x;   // 0..31
  const int h = blockIdx.y;    // 0..15
  const int q0 = qb * 64;
  const int g = h >> 2;        // kv head
  __shared__ u16 Qs[64 * 72], Ks[64 * 72], Vt[64 * 72], Ps[64 * 72];
  const int tid = threadIdx.x, wid = tid >> 6, lane = tid & 63;
  const int quad = lane >> 4, l16 = lane & 15;

#pragma unroll
  for (int it = 0; it < 2; ++it) {
    int idx = it * 256 + tid;
    int row = idx >> 3, c8 = (idx & 7) * 8;
    *(short8*)&Qs[row * 72 + c8] =
        *(const short8*)&qkv[(size_t)(q0 + row) * QKVD + h * 64 + c8];
  }

  f32x4 oacc[4] = {};
  float mrun[4], lrun[4];
#pragma unroll
  for (int r = 0; r < 4; ++r) { mrun[r] = -1e30f; lrun[r] = 0.f; }

  const int ktlo = (q0 >= WINSZ) ? ((q0 - WINSZ + 1) >> 6) : 0;
  const int kthi = qb;
  for (int kt = ktlo; kt <= kthi; ++kt) {
#pragma unroll
    for (int it = 0; it < 2; ++it) {
      int idx = it * 256 + tid;
      int row = idx >> 3, c8 = (idx & 7) * 8;
      *(short8*)&Ks[row * 72 + c8] =
          *(const short8*)&qkv[(size_t)(kt * 64 + row) * QKVD + 1024 + g * 64 + c8];
    }
#pragma unroll
    for (int it = 0; it < 8; ++it) {
      int idx = it * 256 + tid;
      int key = idx >> 5;
      int d = (idx & 31) * 2;
      unsigned int u = *(const unsigned int*)&qkv[(size_t)(kt * 64 + key) * QKVD + 1280 + g * 64 + d];
      Vt[d * 72 + key] = (u16)(u & 0xffffu);
      Vt[(d + 1) * 72 + key] = (u16)(u >> 16);
    }
    __syncthreads();

    f32x4 sa[4] = {};
#pragma unroll
    for (int ks = 0; ks < 2; ++ks) {
      short8 af = *(const short8*)&Qs[(16 * wid + l16) * 72 + ks * 32 + quad * 8];
#pragma unroll
      for (int ct = 0; ct < 4; ++ct) {
        short8 bf = *(const short8*)&Ks[(16 * ct + l16) * 72 + ks * 32 + quad * 8];
        sa[ct] = MFMA_BF16(af, bf, sa[ct]);
      }
    }

    float pvv[4][4];
#pragma unroll
    for (int r = 0; r < 4; ++r) {
      int i = q0 + 16 * wid + quad * 4 + r;
      float mx = -1e30f;
#pragma unroll
      for (int ct = 0; ct < 4; ++ct) {
        int j = kt * 64 + 16 * ct + l16;
        float v = sa[ct][r] * 0.125f;
        bool ok = (j <= i) && (i - j < WINSZ);
        v = ok ? v : -1e30f;
        pvv[ct][r] = v;
        mx = fmaxf(mx, v);
      }
#pragma unroll
      for (int m = 1; m < 16; m <<= 1) mx = fmaxf(mx, __shfl_xor(mx, m));
      float mnew = fmaxf(mrun[r], mx);
      float alpha = __expf(mrun[r] - mnew);
      float s = 0.f;
#pragma unroll
      for (int ct = 0; ct < 4; ++ct) {
        float p = (pvv[ct][r] > -1e29f) ? __expf(pvv[ct][r] - mnew) : 0.f;
        pvv[ct][r] = p;
        s += p;
      }
#pragma unroll
      for (int m = 1; m < 16; m <<= 1) s += __shfl_xor(s, m);
      lrun[r] = lrun[r] * alpha + s;
      mrun[r] = mnew;
#pragma unroll
      for (int ct = 0; ct < 4; ++ct) oacc[ct][r] *= alpha;
    }
#pragma unroll
    for (int ct = 0; ct < 4; ++ct)
#pragma unroll
      for (int r = 0; r < 4; ++r)
        Ps[(16 * wid + quad * 4 + r) * 72 + 16 * ct + l16] = f2bf(pvv[ct][r]);
    __syncthreads();

#pragma unroll
    for (int ks = 0; ks < 2; ++ks) {
      short8 af = *(const short8*)&Ps[(16 * wid + l16) * 72 + ks * 32 + quad * 8];
#pragma unroll
      for (int ct = 0; ct < 4; ++ct) {
        short8 bf = *(const short8*)&Vt[(16 * ct + l16) * 72 + ks * 32 + quad * 8];
        oacc[ct] = MFMA_BF16(af, bf, oacc[ct]);
      }
    }
    __syncthreads();
  }

#pragma unroll
  for (int ct = 0; ct < 4; ++ct)
#pragma unroll
    for (int r = 0; r < 4; ++r) {
      int row = q0 + 16 * wid + quad * 4 + r;
      float v = oacc[ct][r] / lrun[r];
      o[(size_t)row * HID + h * 64 + 16 * ct + l16] = f2bf(v);
    }
}

// --------- RMSNorm2 + router top-2 (sums O-proj splits + residual) -------
__global__ __launch_bounds__(256) void k_rms2_router(
    const float* __restrict__ o0, const float* __restrict__ o1,
    const float* __restrict__ hs, const float* __restrict__ ln2,
    const float* __restrict__ rw, float* __restrict__ out1,
    u16* __restrict__ T, int* __restrict__ counts,
    int* __restrict__ tok_idx, float* __restrict__ tok_w) {
  const int tkn = blockIdx.x, tid = threadIdx.x, wid = tid >> 6, lane = tid & 63;
  const size_t base = (size_t)tkn * HID + tid * 4;
  float4 a = *(const float4*)&o0[base];
  float4 b = *(const float4*)&o1[base];
  float4 h = *(const float4*)&hs[base];
  float4 v;
  v.x = a.x + b.x + h.x; v.y = a.y + b.y + h.y;
  v.z = a.z + b.z + h.z; v.w = a.w + b.w + h.w;
  *(float4*)&out1[base] = v;
  float ss = v.x * v.x + v.y * v.y + v.z * v.z + v.w * v.w;
#pragma unroll
  for (int m = 1; m < 64; m <<= 1) ss += __shfl_xor(ss, m);
  __shared__ float red[4];
  if (lane == 0) red[wid] = ss;
  __syncthreads();
  ss = red[0] + red[1] + red[2] + red[3];
  float sc = rsqrtf(ss * (1.0f / HID) + EPSF);
  float4 lw = *(const float4*)&ln2[tid * 4];
  float t0 = v.x * sc * lw.x;
  float t1 = v.y * sc * lw.y;
  float t2 = v.z * sc * lw.z;
  float t3 = v.w * sc * lw.w;
  ushort4 o;
  o.x = f2bf(t0); o.y = f2bf(t1); o.z = f2bf(t2); o.w = f2bf(t3);
  *(ushort4*)&T[(size_t)tkn * HID + tid * 4] = o;

  float p[8];
#pragma unroll
  for (int e = 0; e < 8; ++e) {
    float4 r = *(const float4*)&rw[e * HID + tid * 4];
    p[e] = t0 * r.x + t1 * r.y + t2 * r.z + t3 * r.w;
  }
#pragma unroll
  for (int e = 0; e < 8; ++e)
#pragma unroll
    for (int m = 1; m < 64; m <<= 1) p[e] += __shfl_xor(p[e], m);
  __shared__ float pr[4][8];
  if (lane == 0)
#pragma unroll
    for (int e = 0; e < 8; ++e) pr[wid][e] = p[e];
  __syncthreads();
  if (tid == 0) {
    float lg[8];
#pragma unroll
    for (int e = 0; e < 8; ++e) lg[e] = pr[0][e] + pr[1][e] + pr[2][e] + pr[3][e];
    float mx = lg[0];
#pragma unroll
    for (int e = 1; e < 8; ++e) mx = fmaxf(mx, lg[e]);
    float ex[8], se = 0.f;
#pragma unroll
    for (int e = 0; e < 8; ++e) { ex[e] = __expf(lg[e] - mx); se += ex[e]; }
    int b0 = 0;
#pragma unroll
    for (int e = 1; e < 8; ++e) if (lg[e] > lg[b0]) b0 = e;
    int b1 = (b0 == 0) ? 1 : 0;
#pragma unroll
    for (int e = 0; e < 8; ++e) if (e != b0 && lg[e] > lg[b1]) b1 = e;
    float inv = 1.0f / se;
    int s0 = atomicAdd(&counts[b0], 1);
    tok_idx[b0 * SEQ + s0] = tkn;
    tok_w[b0 * SEQ + s0] = ex[b0] * inv;
    int s1 = atomicAdd(&counts[b1], 1);
    tok_idx[b1 * SEQ + s1] = tkn;
    tok_w[b1 * SEQ + s1] = ex[b1] * inv;
  }
}

__global__ void k_offsets(const int* __restrict__ counts, int* __restrict__ offs) {
  if (threadIdx.x == 0 && blockIdx.x == 0) {
    int s = 0;
    for (int e = 0; e < NEXP; ++e) { offs[e] = s; s += counts[e]; }
    offs[NEXP] = s;
  }
}

// -------- MoE up GEMM (gathered A, n-tile 64) + fused SiLU*u --------
__global__ __launch_bounds__(256, 3) void k_moe_gu(
    const u16* __restrict__ T, const u16* __restrict__ Wgu,
    const int* __restrict__ counts, const int* __restrict__ offs,
    const int* __restrict__ tok_idx, u16* __restrict__ Abuf) {
  const int e = blockIdx.z;
  const int cnt = counts[e];
  const int m0 = blockIdx.y * 128;
  if (m0 >= cnt) return;
  const int n0 = blockIdx.x * 64;
  const u16* We = Wgu + (size_t)e * 2 * FFI * HID;
  const int* ti = tok_idx + e * SEQ;
  const int aoff = offs[e];
  __shared__ u16 As[128 * 64], Bg[64 * 64], Bu[64 * 64];
  const int tid = threadIdx.x, wid = tid >> 6, lane = tid & 63;
  const int quad = lane >> 4, l16 = lane & 15;
  const int wr = wid >> 1, wc = wid & 1;  // wave tile: 64m x 32n
  const int sr = lane >> 3, sc = (lane & 7) * 8;
  int tokrow[4];
#pragma unroll
  for (int it = 0; it < 4; ++it) {
    int row = (wid * 4 + it) * 8 + sr;
    int ra = m0 + row;
    if (ra > cnt - 1) ra = cnt - 1;
    tokrow[it] = ti[ra];
  }
  f32x4 accg[4][2] = {}, accu[4][2] = {};
  for (int kt = 0; kt < 16; ++kt) {
    const int k0 = kt << 6;
#pragma unroll
    for (int it = 0; it < 4; ++it) {
      int seg = wid * 4 + it;
      gload_lds16(&T[(size_t)tokrow[it] * HID + k0 + sc], &As[seg * 512]);
    }
#pragma unroll
    for (int it = 0; it < 2; ++it) {
      int seg = wid * 2 + it;
      int row = seg * 8 + sr;
      gload_lds16(&We[(size_t)(n0 + row) * HID + k0 + sc], &Bg[seg * 512]);
      gload_lds16(&We[(size_t)(FFI + n0 + row) * HID + k0 + sc], &Bu[seg * 512]);
    }
    __syncthreads();
#pragma unroll
    for (int ks = 0; ks < 2; ++ks) {
      short8 af[4], bg[2], bu[2];
#pragma unroll
      for (int t = 0; t < 4; ++t)
        af[t] = *(const short8*)&As[(64 * wr + 16 * t + l16) * 64 + ks * 32 + quad * 8];
#pragma unroll
      for (int t = 0; t < 2; ++t) {
        bg[t] = *(const short8*)&Bg[(32 * wc + 16 * t + l16) * 64 + ks * 32 + quad * 8];
        bu[t] = *(const short8*)&Bu[(32 * wc + 16 * t + l16) * 64 + ks * 32 + quad * 8];
      }
#pragma unroll
      for (int mt = 0; mt < 4; ++mt)
#pragma unroll
        for (int nt = 0; nt < 2; ++nt) {
          accg[mt][nt] = MFMA_BF16(af[mt], bg[nt], accg[mt][nt]);
          accu[mt][nt] = MFMA_BF16(af[mt], bu[nt], accu[mt][nt]);
        }
    }
    __syncthreads();
  }
#pragma unroll
  for (int mt = 0; mt < 4; ++mt)
#pragma unroll
    for (int r = 0; r < 4; ++r) {
      int rl = 64 * wr + 16 * mt + quad * 4 + r;
      int grow = m0 + rl;
      if (grow < cnt) {
        size_t rbase = (size_t)(aoff + grow) * FFI;
#pragma unroll
        for (int nt = 0; nt < 2; ++nt) {
          int col = n0 + 32 * wc + 16 * nt + l16;
          float gv = accg[mt][nt][r];
          float uv = accu[mt][nt][r];
          float a = gv / (1.0f + __expf(-gv)) * uv;
          Abuf[rbase + col] = f2bf(a);
        }
      }
    }
}

// ------ MoE down GEMM, split-K x4, weighted atomic scatter (f32 out) -----
__global__ __launch_bounds__(256, 2) void k_moe_y(
    const u16* __restrict__ Abuf, const u16* __restrict__ W2,
    const int* __restrict__ counts, const int* __restrict__ offs,
    const int* __restrict__ tok_idx, const float* __restrict__ tok_w,
    float* __restrict__ outf) {
  const int e = blockIdx.z >> 2;
  const int sk = blockIdx.z & 3;
  const int cnt = counts[e];
  const int m0 = blockIdx.y * 128;
  if (m0 >= cnt) return;
  const int n0 = blockIdx.x * 128;
  const int kbase = sk * 704;   // 2816 / 4
  const u16* We = W2 + (size_t)e * HID * FFI;
  const int aoff = offs[e];
  __shared__ u16 As[128 * 64], Bs[128 * 64];
  const int tid = threadIdx.x, wid = tid >> 6, lane = tid & 63;
  const int quad = lane >> 4, l16 = lane & 15;
  const int wr = wid >> 1, wc = wid & 1;
  const int sr = lane >> 3, sc = (lane & 7) * 8;
  int arow[4];
#pragma unroll
  for (int it = 0; it < 4; ++it) {
    int row = (wid * 4 + it) * 8 + sr;
    int ra = m0 + row;
    if (ra > cnt - 1) ra = cnt - 1;
    arow[it] = aoff + ra;
  }
  f32x4 acc[4][4] = {};
  for (int kt = 0; kt < 11; ++kt) {
    const int k0 = kbase + (kt << 6);
#pragma unroll
    for (int it = 0; it < 4; ++it) {
      int seg = wid * 4 + it;
      int row = seg * 8 + sr;
      gload_lds16(&Abuf[(size_t)arow[it] * FFI + k0 + sc], &As[seg * 512]);
      gload_lds16(&We[(size_t)(n0 + row) * FFI + k0 + sc], &Bs[seg * 512]);
    }
    __syncthreads();
#pragma unroll
    for (int ks = 0; ks < 2; ++ks) {
      short8 af[4], bf[4];
#pragma unroll
      for (int t = 0; t < 4; ++t)
        af[t] = *(const short8*)&As[(64 * wr + 16 * t + l16) * 64 + ks * 32 + quad * 8];
#pragma unroll
      for (int t = 0; t < 4; ++t)
        bf[t] = *(const short8*)&Bs[(64 * wc + 16 * t + l16) * 64 + ks * 32 + quad * 8];
#pragma unroll
      for (int mt = 0; mt < 4; ++mt)
#pragma unroll
        for (int nt = 0; nt < 4; ++nt)
          acc[mt][nt] = MFMA_BF16(af[mt], bf[nt], acc[mt][nt]);
    }
    __syncthreads();
  }
#pragma unroll
  for (int mt = 0; mt < 4; ++mt)
#pragma unroll
    for (int r = 0; r < 4; ++r) {
      int rl = 64 * wr + 16 * mt + quad * 4 + r;
      int grow = m0 + rl;
      if (grow < cnt) {
        int tok = tok_idx[e * SEQ + grow];
        float wgt = tok_w[e * SEQ + grow];
        size_t obase = (size_t)tok * HID;
#pragma unroll
        for (int nt = 0; nt < 4; ++nt) {
          int col = n0 + 64 * wc + 16 * nt + l16;
          atomicAdd(&outf[obase + col], wgt * acc[mt][nt][r]);
        }
      }
    }
}

extern "C" void kernel_launch(void* const* d_in, const int* in_sizes, int n_in,
                              void* d_out, int out_size, void* d_ws, size_t ws_size,
                              hipStream_t stream) {
  const float* hs   = (const float*)d_in[0];
  const float* wqkv = (const float*)d_in[2];
  const float* wo   = (const float*)d_in[3];
  const float* rwt  = (const float*)d_in[4];
  const float* wsx  = (const float*)d_in[5];
  const float* w2s  = (const float*)d_in[6];
  const float* ln1  = (const float*)d_in[7];
  const float* ln2  = (const float*)d_in[8];
  float* out0 = (float*)d_out;                       // MoE output (f32)
  float* out1 = out0 + (size_t)SEQ * HID;            // residual2 (f32)

  char* p = (char*)d_ws;
  u16* xn      = (u16*)p;   p += (size_t)SEQ * HID * 2;
  u16* qkv     = (u16*)p;   p += (size_t)SEQ * QKVD * 2;
  u16* ob      = (u16*)p;   p += (size_t)SEQ * HID * 2;
  float* qkvf  = (float*)p; p += (size_t)2 * SEQ * QKVD * 4;   // also re-used for oacc
  int* counts  = (int*)p;   p += 32;
  int* offs    = (int*)p;   p += 64;
  int* tok_idx = (int*)p;   p += (size_t)NEXP * SEQ * 4;
  float* tok_w = (float*)p; p += (size_t)NEXP * SEQ * 4;
  u16* abuf    = (u16*)p;   p += (size_t)2 * SEQ * FFI * 2;
  u16* wqkv_b  = (u16*)p;   p += (size_t)QKVD * HID * 2;
  u16* wo_b    = (u16*)p;   p += (size_t)HID * HID * 2;
  u16* ws_b    = (u16*)p;   p += (size_t)NEXP * 2 * FFI * HID * 2;
  u16* w2s_b   = (u16*)p;   p += (size_t)NEXP * HID * FFI * 2;

  u16* tb      = xn;                       // alias: xn dead after QKV GEMM
  float* oacc0 = qkvf;                     // alias: qkvf dead after k_sum2_bf16
  float* oacc1 = qkvf + (size_t)SEQ * HID;

  hipMemsetAsync(counts, 0, 32, stream);
  hipMemsetAsync(out0, 0, (size_t)SEQ * HID * 4, stream);

  k_f2b_all<<<(CNT_ALL + 255) / 256, 256, 0, stream>>>(
      wqkv, wo, wsx, w2s, wqkv_b, wo_b, ws_b, w2s_b);

  k_rmsnorm<<<SEQ, 256, 0, stream>>>(hs, ln1, xn);
  // QKV: M=2048, N=1536, K=1024, split-K x2
  k_gemm_bt_sk<<<dim3(QKVD / 128, SEQ / 128, 2), 256, 0, stream>>>(
      xn, wqkv_b, qkvf, QKVD, HID, 512);
  k_sum2_bf16<<<(SEQ * QKVD / 4 + 255) / 256, 256, 0, stream>>>(
      qkvf, qkvf + (size_t)SEQ * QKVD, qkv, SEQ * QKVD / 4);
  k_attn<<<dim3(SEQ / 64, NHEAD), 256, 0, stream>>>(qkv, ob);
  // O-proj: M=2048, N=1024, K=1024, split-K x2 (sum fused into rms2_router)
  k_gemm_bt_sk<<<dim3(HID / 128, SEQ / 128, 2), 256, 0, stream>>>(
      ob, wo_b, oacc0, HID, HID, 512);
  k_rms2_router<<<SEQ, 256, 0, stream>>>(oacc0, oacc1, hs, ln2, rwt, out1, tb,
                                         counts, tok_idx, tok_w);
  k_offsets<<<1, 64, 0, stream>>>(counts, offs);
  k_moe_gu<<<dim3(FFI / 64, SEQ / 128, NEXP), 256, 0, stream>>>(
      tb, ws_b, counts, offs, tok_idx, abuf);
  k_moe_y<<<dim3(HID / 128, SEQ / 128, NEXP * 4), 256, 0, stream>>>(
      abuf, w2s_b, counts, offs, tok_idx, tok_w, out0);
}

// Round 4
// 635.326 us; speedup vs baseline: 1.2061x; 1.0410x over previous
//
#include <hip/hip_runtime.h>
#include <stdint.h>

typedef unsigned short u16;
typedef __attribute__((ext_vector_type(8))) short short8;
typedef __attribute__((ext_vector_type(4))) float f32x4;

constexpr int SEQ   = 2048;
constexpr int HID   = 1024;
constexpr int NHEAD = 16;
constexpr int QKVD  = 1536;   // (16 + 2*4) * 64
constexpr int FFI   = 2816;
constexpr int NEXP  = 8;
constexpr int WINSZ = 512;
#define EPSF 1e-5f

__device__ __forceinline__ float bf2f(u16 u) {
  union { unsigned int i; float f; } v; v.i = ((unsigned int)u) << 16; return v.f;
}
__device__ __forceinline__ u16 f2bf(float f) {
  union { unsigned int i; float f; } v; v.f = f;
  unsigned int i = v.i;
  return (u16)((i + 0x7fffu + ((i >> 16) & 1u)) >> 16);
}

__device__ __forceinline__ void gload_lds16(const void* g, void* l) {
  __builtin_amdgcn_global_load_lds((__attribute__((address_space(1))) void*)g,
                                   (__attribute__((address_space(3))) void*)l,
                                   16, 0, 0);
}

#define MFMA_BF16(a, b, c) __builtin_amdgcn_mfma_f32_16x16x32_bf16(a, b, c, 0, 0, 0)

// sizes in float4 units
constexpr int CN1 = QKVD * HID / 4;            // wqkv
constexpr int CN2 = HID * HID / 4;             // wo
constexpr int CN3 = NEXP * 2 * FFI * HID / 4;  // ws
constexpr int CN4 = NEXP * HID * FFI / 4;      // w2s
constexpr int CN_SMALL = CN1 + CN2;            // 655360
constexpr int CN_BIG   = CN3 + CN4;            // 17301504
constexpr int NCONV_BLK = CN_BIG / 1024;       // 16896 (4 f4-units/thread)
constexpr int NATTN_BLK = (SEQ / 64) * NHEAD;  // 512

// ---------------- small weight f32 -> bf16 (wqkv, wo) ----------------
__global__ __launch_bounds__(256) void k_f2b_small(
    const float* __restrict__ wqkv, const float* __restrict__ wo,
    u16* __restrict__ dq, u16* __restrict__ dwo) {
  int j = (blockIdx.x * 256 + threadIdx.x) * 4;  // f4 unit
#pragma unroll
  for (int t = 0; t < 4; ++t, ++j) {
    if (j >= CN_SMALL) return;
    const float* s; u16* d; int i = j;
    if (i < CN1) { s = wqkv; d = dq; } else { i -= CN1; s = wo; d = dwo; }
    float4 v = ((const float4*)s)[i];
    ushort4 o;
    o.x = f2bf(v.x); o.y = f2bf(v.y); o.z = f2bf(v.z); o.w = f2bf(v.w);
    ((ushort4*)d)[i] = o;
  }
}

// ---------------- RMSNorm (f32 in -> bf16 out) ----------------
__global__ __launch_bounds__(256) void k_rmsnorm(const float* __restrict__ x,
                                                 const float* __restrict__ w,
                                                 u16* __restrict__ y) {
  const int tkn = blockIdx.x, tid = threadIdx.x, wid = tid >> 6, lane = tid & 63;
  const float* xr = x + (size_t)tkn * HID;
  float4 v = *(const float4*)&xr[tid * 4];
  float ss = v.x * v.x + v.y * v.y + v.z * v.z + v.w * v.w;
#pragma unroll
  for (int m = 1; m < 64; m <<= 1) ss += __shfl_xor(ss, m);
  __shared__ float red[4];
  if (lane == 0) red[wid] = ss;
  __syncthreads();
  ss = red[0] + red[1] + red[2] + red[3];
  float sc = rsqrtf(ss * (1.0f / HID) + EPSF);
  float4 wv = *(const float4*)&w[tid * 4];
  ushort4 o;
  o.x = f2bf(v.x * sc * wv.x);
  o.y = f2bf(v.y * sc * wv.y);
  o.z = f2bf(v.z * sc * wv.z);
  o.w = f2bf(v.w * sc * wv.w);
  *(ushort4*)&y[(size_t)tkn * HID + tid * 4] = o;
}

// ------------- split-K C = A * B^T GEMM, f32 partial out per split -------
__global__ __launch_bounds__(256, 2) void k_gemm_bt_sk(
    const u16* __restrict__ A, const u16* __restrict__ B, float* __restrict__ Cf,
    int N, int K, int Kc) {
  __shared__ u16 As[128 * 64];
  __shared__ u16 Bs[128 * 64];
  const int tid = threadIdx.x, wid = tid >> 6, lane = tid & 63;
  const int quad = lane >> 4, l16 = lane & 15;
  const int wr = wid >> 1, wc = wid & 1;
  const int m0 = blockIdx.y * 128, n0 = blockIdx.x * 128;
  const int M = gridDim.y * 128;
  const int kbase = blockIdx.z * Kc;
  const int sr = lane >> 3, sc = (lane & 7) * 8;
  f32x4 acc[4][4] = {};
  const int KT = Kc >> 6;
  for (int kt = 0; kt < KT; ++kt) {
    const int k0 = kbase + (kt << 6);
#pragma unroll
    for (int it = 0; it < 4; ++it) {
      int seg = wid * 4 + it;
      int row = seg * 8 + sr;
      gload_lds16(&A[(size_t)(m0 + row) * K + k0 + sc], &As[seg * 512]);
      gload_lds16(&B[(size_t)(n0 + row) * K + k0 + sc], &Bs[seg * 512]);
    }
    __syncthreads();
#pragma unroll
    for (int ks = 0; ks < 2; ++ks) {
      short8 af[4], bf[4];
#pragma unroll
      for (int t = 0; t < 4; ++t)
        af[t] = *(const short8*)&As[(64 * wr + 16 * t + l16) * 64 + ks * 32 + quad * 8];
#pragma unroll
      for (int t = 0; t < 4; ++t)
        bf[t] = *(const short8*)&Bs[(64 * wc + 16 * t + l16) * 64 + ks * 32 + quad * 8];
#pragma unroll
      for (int mt = 0; mt < 4; ++mt)
#pragma unroll
        for (int nt = 0; nt < 4; ++nt)
          acc[mt][nt] = MFMA_BF16(af[mt], bf[nt], acc[mt][nt]);
    }
    __syncthreads();
  }
  float* Co = Cf + (size_t)blockIdx.z * M * N;
#pragma unroll
  for (int mt = 0; mt < 4; ++mt)
#pragma unroll
    for (int r = 0; r < 4; ++r) {
      int row = m0 + 64 * wr + 16 * mt + quad * 4 + r;
#pragma unroll
      for (int nt = 0; nt < 4; ++nt) {
        int col = n0 + 64 * wc + 16 * nt + l16;
        Co[(size_t)row * N + col] = acc[mt][nt][r];
      }
    }
}

// ---------------- sum 2 split halves -> bf16 ----------------
__global__ __launch_bounds__(256) void k_sum2_bf16(const float* __restrict__ a,
                                                   const float* __restrict__ b,
                                                   u16* __restrict__ o, int n4) {
  int i = blockIdx.x * 256 + threadIdx.x;
  if (i >= n4) return;
  float4 x = ((const float4*)a)[i];
  float4 y = ((const float4*)b)[i];
  ushort4 u;
  u.x = f2bf(x.x + y.x); u.y = f2bf(x.y + y.y);
  u.z = f2bf(x.z + y.z); u.w = f2bf(x.w + y.w);
  ((ushort4*)o)[i] = u;
}

// ------- sliding-window GQA flash attention + fused big-weight convert ----
// flattened grid: blocks [0, NATTN_BLK) do attention; the rest convert ws/w2s.
__global__ __launch_bounds__(256, 2) void k_attn_conv(
    const u16* __restrict__ qkv, u16* __restrict__ o,
    const float* __restrict__ ws, const float* __restrict__ w2s,
    u16* __restrict__ dws, u16* __restrict__ dw2) {
  const int bid = blockIdx.x;
  const int tid = threadIdx.x;
  if (bid >= NATTN_BLK) {
    // ---- conversion path: 4 float4 units (16 floats) per thread ----
    int j = (bid - NATTN_BLK) * 1024 + tid * 4;
    const float* s; u16* d;
    if (j < CN3) { s = ws; d = dws; } else { j -= CN3; s = w2s; d = dw2; }
    float4 v0 = ((const float4*)s)[j + 0];
    float4 v1 = ((const float4*)s)[j + 1];
    float4 v2 = ((const float4*)s)[j + 2];
    float4 v3 = ((const float4*)s)[j + 3];
    ushort4 o0, o1, o2, o3;
    o0.x = f2bf(v0.x); o0.y = f2bf(v0.y); o0.z = f2bf(v0.z); o0.w = f2bf(v0.w);
    o1.x = f2bf(v1.x); o1.y = f2bf(v1.y); o1.z = f2bf(v1.z); o1.w = f2bf(v1.w);
    o2.x = f2bf(v2.x); o2.y = f2bf(v2.y); o2.z = f2bf(v2.z); o2.w = f2bf(v2.w);
    o3.x = f2bf(v3.x); o3.y = f2bf(v3.y); o3.z = f2bf(v3.z); o3.w = f2bf(v3.w);
    ((ushort4*)d)[j + 0] = o0;
    ((ushort4*)d)[j + 1] = o1;
    ((ushort4*)d)[j + 2] = o2;
    ((ushort4*)d)[j + 3] = o3;
    return;
  }
  const int qb = bid & 31;          // 0..31
  const int h  = bid >> 5;          // 0..15
  const int q0 = qb * 64;
  const int g = h >> 2;             // kv head
  __shared__ u16 Qs[64 * 72], Ks[64 * 72], Vt[64 * 72], Ps[64 * 72];
  const int wid = tid >> 6, lane = tid & 63;
  const int quad = lane >> 4, l16 = lane & 15;

#pragma unroll
  for (int it = 0; it < 2; ++it) {
    int idx = it * 256 + tid;
    int row = idx >> 3, c8 = (idx & 7) * 8;
    *(short8*)&Qs[row * 72 + c8] =
        *(const short8*)&qkv[(size_t)(q0 + row) * QKVD + h * 64 + c8];
  }

  f32x4 oacc[4] = {};
  float mrun[4], lrun[4];
#pragma unroll
  for (int r = 0; r < 4; ++r) { mrun[r] = -1e30f; lrun[r] = 0.f; }

  const int ktlo = (q0 >= WINSZ) ? ((q0 - WINSZ + 1) >> 6) : 0;
  const int kthi = qb;
  for (int kt = ktlo; kt <= kthi; ++kt) {
#pragma unroll
    for (int it = 0; it < 2; ++it) {
      int idx = it * 256 + tid;
      int row = idx >> 3, c8 = (idx & 7) * 8;
      *(short8*)&Ks[row * 72 + c8] =
          *(const short8*)&qkv[(size_t)(kt * 64 + row) * QKVD + 1024 + g * 64 + c8];
    }
#pragma unroll
    for (int it = 0; it < 8; ++it) {
      int idx = it * 256 + tid;
      int key = idx >> 5;
      int d = (idx & 31) * 2;
      unsigned int u = *(const unsigned int*)&qkv[(size_t)(kt * 64 + key) * QKVD + 1280 + g * 64 + d];
      Vt[d * 72 + key] = (u16)(u & 0xffffu);
      Vt[(d + 1) * 72 + key] = (u16)(u >> 16);
    }
    __syncthreads();

    f32x4 sa[4] = {};
#pragma unroll
    for (int ks = 0; ks < 2; ++ks) {
      short8 af = *(const short8*)&Qs[(16 * wid + l16) * 72 + ks * 32 + quad * 8];
#pragma unroll
      for (int ct = 0; ct < 4; ++ct) {
        short8 bf = *(const short8*)&Ks[(16 * ct + l16) * 72 + ks * 32 + quad * 8];
        sa[ct] = MFMA_BF16(af, bf, sa[ct]);
      }
    }

    float pvv[4][4];
#pragma unroll
    for (int r = 0; r < 4; ++r) {
      int i = q0 + 16 * wid + quad * 4 + r;
      float mx = -1e30f;
#pragma unroll
      for (int ct = 0; ct < 4; ++ct) {
        int j = kt * 64 + 16 * ct + l16;
        float v = sa[ct][r] * 0.125f;
        bool ok = (j <= i) && (i - j < WINSZ);
        v = ok ? v : -1e30f;
        pvv[ct][r] = v;
        mx = fmaxf(mx, v);
      }
#pragma unroll
      for (int m = 1; m < 16; m <<= 1) mx = fmaxf(mx, __shfl_xor(mx, m));
      float mnew = fmaxf(mrun[r], mx);
      float alpha = __expf(mrun[r] - mnew);
      float s = 0.f;
#pragma unroll
      for (int ct = 0; ct < 4; ++ct) {
        float p = (pvv[ct][r] > -1e29f) ? __expf(pvv[ct][r] - mnew) : 0.f;
        pvv[ct][r] = p;
        s += p;
      }
#pragma unroll
      for (int m = 1; m < 16; m <<= 1) s += __shfl_xor(s, m);
      lrun[r] = lrun[r] * alpha + s;
      mrun[r] = mnew;
#pragma unroll
      for (int ct = 0; ct < 4; ++ct) oacc[ct][r] *= alpha;
    }
#pragma unroll
    for (int ct = 0; ct < 4; ++ct)
#pragma unroll
      for (int r = 0; r < 4; ++r)
        Ps[(16 * wid + quad * 4 + r) * 72 + 16 * ct + l16] = f2bf(pvv[ct][r]);
    __syncthreads();

#pragma unroll
    for (int ks = 0; ks < 2; ++ks) {
      short8 af = *(const short8*)&Ps[(16 * wid + l16) * 72 + ks * 32 + quad * 8];
#pragma unroll
      for (int ct = 0; ct < 4; ++ct) {
        short8 bf = *(const short8*)&Vt[(16 * ct + l16) * 72 + ks * 32 + quad * 8];
        oacc[ct] = MFMA_BF16(af, bf, oacc[ct]);
      }
    }
    __syncthreads();
  }

#pragma unroll
  for (int ct = 0; ct < 4; ++ct)
#pragma unroll
    for (int r = 0; r < 4; ++r) {
      int row = q0 + 16 * wid + quad * 4 + r;
      float v = oacc[ct][r] / lrun[r];
      o[(size_t)row * HID + h * 64 + 16 * ct + l16] = f2bf(v);
    }
}

// --------- RMSNorm2 + router top-2 (sums O-proj splits + residual) -------
__global__ __launch_bounds__(256) void k_rms2_router(
    const float* __restrict__ o0, const float* __restrict__ o1,
    const float* __restrict__ hs, const float* __restrict__ ln2,
    const float* __restrict__ rw, float* __restrict__ out1,
    u16* __restrict__ T, int* __restrict__ counts,
    int* __restrict__ tok_idx, float* __restrict__ tok_w) {
  const int tkn = blockIdx.x, tid = threadIdx.x, wid = tid >> 6, lane = tid & 63;
  const size_t base = (size_t)tkn * HID + tid * 4;
  float4 a = *(const float4*)&o0[base];
  float4 b = *(const float4*)&o1[base];
  float4 h = *(const float4*)&hs[base];
  float4 v;
  v.x = a.x + b.x + h.x; v.y = a.y + b.y + h.y;
  v.z = a.z + b.z + h.z; v.w = a.w + b.w + h.w;
  *(float4*)&out1[base] = v;
  float ss = v.x * v.x + v.y * v.y + v.z * v.z + v.w * v.w;
#pragma unroll
  for (int m = 1; m < 64; m <<= 1) ss += __shfl_xor(ss, m);
  __shared__ float red[4];
  if (lane == 0) red[wid] = ss;
  __syncthreads();
  ss = red[0] + red[1] + red[2] + red[3];
  float sc = rsqrtf(ss * (1.0f / HID) + EPSF);
  float4 lw = *(const float4*)&ln2[tid * 4];
  float t0 = v.x * sc * lw.x;
  float t1 = v.y * sc * lw.y;
  float t2 = v.z * sc * lw.z;
  float t3 = v.w * sc * lw.w;
  ushort4 o;
  o.x = f2bf(t0); o.y = f2bf(t1); o.z = f2bf(t2); o.w = f2bf(t3);
  *(ushort4*)&T[(size_t)tkn * HID + tid * 4] = o;

  float p[8];
#pragma unroll
  for (int e = 0; e < 8; ++e) {
    float4 r = *(const float4*)&rw[e * HID + tid * 4];
    p[e] = t0 * r.x + t1 * r.y + t2 * r.z + t3 * r.w;
  }
#pragma unroll
  for (int e = 0; e < 8; ++e)
#pragma unroll
    for (int m = 1; m < 64; m <<= 1) p[e] += __shfl_xor(p[e], m);
  __shared__ float pr[4][8];
  if (lane == 0)
#pragma unroll
    for (int e = 0; e < 8; ++e) pr[wid][e] = p[e];
  __syncthreads();
  if (tid == 0) {
    float lg[8];
#pragma unroll
    for (int e = 0; e < 8; ++e) lg[e] = pr[0][e] + pr[1][e] + pr[2][e] + pr[3][e];
    float mx = lg[0];
#pragma unroll
    for (int e = 1; e < 8; ++e) mx = fmaxf(mx, lg[e]);
    float ex[8], se = 0.f;
#pragma unroll
    for (int e = 0; e < 8; ++e) { ex[e] = __expf(lg[e] - mx); se += ex[e]; }
    int b0 = 0;
#pragma unroll
    for (int e = 1; e < 8; ++e) if (lg[e] > lg[b0]) b0 = e;
    int b1 = (b0 == 0) ? 1 : 0;
#pragma unroll
    for (int e = 0; e < 8; ++e) if (e != b0 && lg[e] > lg[b1]) b1 = e;
    float inv = 1.0f / se;
    int s0 = atomicAdd(&counts[b0], 1);
    tok_idx[b0 * SEQ + s0] = tkn;
    tok_w[b0 * SEQ + s0] = ex[b0] * inv;
    int s1 = atomicAdd(&counts[b1], 1);
    tok_idx[b1 * SEQ + s1] = tkn;
    tok_w[b1 * SEQ + s1] = ex[b1] * inv;
  }
}

__global__ void k_offsets(const int* __restrict__ counts, int* __restrict__ offs) {
  if (threadIdx.x == 0 && blockIdx.x == 0) {
    int s = 0;
    for (int e = 0; e < NEXP; ++e) { offs[e] = s; s += counts[e]; }
    offs[NEXP] = s;
  }
}

// -------- MoE up GEMM (gathered A, n-tile 64) + fused SiLU*u --------
__global__ __launch_bounds__(256, 2) void k_moe_gu(
    const u16* __restrict__ T, const u16* __restrict__ Wgu,
    const int* __restrict__ counts, const int* __restrict__ offs,
    const int* __restrict__ tok_idx, u16* __restrict__ Abuf) {
  const int e = blockIdx.z;
  const int cnt = counts[e];
  const int m0 = blockIdx.y * 128;
  if (m0 >= cnt) return;
  const int n0 = blockIdx.x * 64;
  const u16* We = Wgu + (size_t)e * 2 * FFI * HID;
  const int* ti = tok_idx + e * SEQ;
  const int aoff = offs[e];
  __shared__ u16 As[128 * 64], Bg[64 * 64], Bu[64 * 64];
  const int tid = threadIdx.x, wid = tid >> 6, lane = tid & 63;
  const int quad = lane >> 4, l16 = lane & 15;
  const int wr = wid >> 1, wc = wid & 1;  // wave tile: 64m x 32n
  const int sr = lane >> 3, sc = (lane & 7) * 8;
  int tokrow[4];
#pragma unroll
  for (int it = 0; it < 4; ++it) {
    int row = (wid * 4 + it) * 8 + sr;
    int ra = m0 + row;
    if (ra > cnt - 1) ra = cnt - 1;
    tokrow[it] = ti[ra];
  }
  f32x4 accg[4][2] = {}, accu[4][2] = {};
  for (int kt = 0; kt < 16; ++kt) {
    const int k0 = kt << 6;
#pragma unroll
    for (int it = 0; it < 4; ++it) {
      int seg = wid * 4 + it;
      gload_lds16(&T[(size_t)tokrow[it] * HID + k0 + sc], &As[seg * 512]);
    }
#pragma unroll
    for (int it = 0; it < 2; ++it) {
      int seg = wid * 2 + it;
      int row = seg * 8 + sr;
      gload_lds16(&We[(size_t)(n0 + row) * HID + k0 + sc], &Bg[seg * 512]);
      gload_lds16(&We[(size_t)(FFI + n0 + row) * HID + k0 + sc], &Bu[seg * 512]);
    }
    __syncthreads();
#pragma unroll
    for (int ks = 0; ks < 2; ++ks) {
      short8 af[4], bg[2], bu[2];
#pragma unroll
      for (int t = 0; t < 4; ++t)
        af[t] = *(const short8*)&As[(64 * wr + 16 * t + l16) * 64 + ks * 32 + quad * 8];
#pragma unroll
      for (int t = 0; t < 2; ++t) {
        bg[t] = *(const short8*)&Bg[(32 * wc + 16 * t + l16) * 64 + ks * 32 + quad * 8];
        bu[t] = *(const short8*)&Bu[(32 * wc + 16 * t + l16) * 64 + ks * 32 + quad * 8];
      }
#pragma unroll
      for (int mt = 0; mt < 4; ++mt)
#pragma unroll
        for (int nt = 0; nt < 2; ++nt) {
          accg[mt][nt] = MFMA_BF16(af[mt], bg[nt], accg[mt][nt]);
          accu[mt][nt] = MFMA_BF16(af[mt], bu[nt], accu[mt][nt]);
        }
    }
    __syncthreads();
  }
#pragma unroll
  for (int mt = 0; mt < 4; ++mt)
#pragma unroll
    for (int r = 0; r < 4; ++r) {
      int rl = 64 * wr + 16 * mt + quad * 4 + r;
      int grow = m0 + rl;
      if (grow < cnt) {
        size_t rbase = (size_t)(aoff + grow) * FFI;
#pragma unroll
        for (int nt = 0; nt < 2; ++nt) {
          int col = n0 + 32 * wc + 16 * nt + l16;
          float gv = accg[mt][nt][r];
          float uv = accu[mt][nt][r];
          float a = gv / (1.0f + __expf(-gv)) * uv;
          Abuf[rbase + col] = f2bf(a);
        }
      }
    }
}

// ------ MoE down GEMM, split-K x4, weighted atomic scatter (f32 out) -----
__global__ __launch_bounds__(256, 2) void k_moe_y(
    const u16* __restrict__ Abuf, const u16* __restrict__ W2,
    const int* __restrict__ counts, const int* __restrict__ offs,
    const int* __restrict__ tok_idx, const float* __restrict__ tok_w,
    float* __restrict__ outf) {
  const int e = blockIdx.z >> 2;
  const int sk = blockIdx.z & 3;
  const int cnt = counts[e];
  const int m0 = blockIdx.y * 128;
  if (m0 >= cnt) return;
  const int n0 = blockIdx.x * 128;
  const int kbase = sk * 704;   // 2816 / 4
  const u16* We = W2 + (size_t)e * HID * FFI;
  const int aoff = offs[e];
  __shared__ u16 As[128 * 64], Bs[128 * 64];
  const int tid = threadIdx.x, wid = tid >> 6, lane = tid & 63;
  const int quad = lane >> 4, l16 = lane & 15;
  const int wr = wid >> 1, wc = wid & 1;
  const int sr = lane >> 3, sc = (lane & 7) * 8;
  int arow[4];
#pragma unroll
  for (int it = 0; it < 4; ++it) {
    int row = (wid * 4 + it) * 8 + sr;
    int ra = m0 + row;
    if (ra > cnt - 1) ra = cnt - 1;
    arow[it] = aoff + ra;
  }
  f32x4 acc[4][4] = {};
  for (int kt = 0; kt < 11; ++kt) {
    const int k0 = kbase + (kt << 6);
#pragma unroll
    for (int it = 0; it < 4; ++it) {
      int seg = wid * 4 + it;
      int row = seg * 8 + sr;
      gload_lds16(&Abuf[(size_t)arow[it] * FFI + k0 + sc], &As[seg * 512]);
      gload_lds16(&We[(size_t)(n0 + row) * FFI + k0 + sc], &Bs[seg * 512]);
    }
    __syncthreads();
#pragma unroll
    for (int ks = 0; ks < 2; ++ks) {
      short8 af[4], bf[4];
#pragma unroll
      for (int t = 0; t < 4; ++t)
        af[t] = *(const short8*)&As[(64 * wr + 16 * t + l16) * 64 + ks * 32 + quad * 8];
#pragma unroll
      for (int t = 0; t < 4; ++t)
        bf[t] = *(const short8*)&Bs[(64 * wc + 16 * t + l16) * 64 + ks * 32 + quad * 8];
#pragma unroll
      for (int mt = 0; mt < 4; ++mt)
#pragma unroll
        for (int nt = 0; nt < 4; ++nt)
          acc[mt][nt] = MFMA_BF16(af[mt], bf[nt], acc[mt][nt]);
    }
    __syncthreads();
  }
#pragma unroll
  for (int mt = 0; mt < 4; ++mt)
#pragma unroll
    for (int r = 0; r < 4; ++r) {
      int rl = 64 * wr + 16 * mt + quad * 4 + r;
      int grow = m0 + rl;
      if (grow < cnt) {
        int tok = tok_idx[e * SEQ + grow];
        float wgt = tok_w[e * SEQ + grow];
        size_t obase = (size_t)tok * HID;
#pragma unroll
        for (int nt = 0; nt < 4; ++nt) {
          int col = n0 + 64 * wc + 16 * nt + l16;
          atomicAdd(&outf[obase + col], wgt * acc[mt][nt][r]);
        }
      }
    }
}

extern "C" void kernel_launch(void* const* d_in, const int* in_sizes, int n_in,
                              void* d_out, int out_size, void* d_ws, size_t ws_size,
                              hipStream_t stream) {
  const float* hs   = (const float*)d_in[0];
  const float* wqkv = (const float*)d_in[2];
  const float* wo   = (const float*)d_in[3];
  const float* rwt  = (const float*)d_in[4];
  const float* wsx  = (const float*)d_in[5];
  const float* w2s  = (const float*)d_in[6];
  const float* ln1  = (const float*)d_in[7];
  const float* ln2  = (const float*)d_in[8];
  float* out0 = (float*)d_out;                       // MoE output (f32)
  float* out1 = out0 + (size_t)SEQ * HID;            // residual2 (f32)

  char* p = (char*)d_ws;
  u16* xn      = (u16*)p;   p += (size_t)SEQ * HID * 2;
  u16* qkv     = (u16*)p;   p += (size_t)SEQ * QKVD * 2;
  u16* ob      = (u16*)p;   p += (size_t)SEQ * HID * 2;
  float* qkvf  = (float*)p; p += (size_t)2 * SEQ * QKVD * 4;   // re-used for oacc
  int* counts  = (int*)p;   p += 32;
  int* offs    = (int*)p;   p += 64;
  int* tok_idx = (int*)p;   p += (size_t)NEXP * SEQ * 4;
  float* tok_w = (float*)p; p += (size_t)NEXP * SEQ * 4;
  u16* abuf    = (u16*)p;   p += (size_t)2 * SEQ * FFI * 2;
  u16* wqkv_b  = (u16*)p;   p += (size_t)QKVD * HID * 2;
  u16* wo_b    = (u16*)p;   p += (size_t)HID * HID * 2;
  u16* ws_b    = (u16*)p;   p += (size_t)NEXP * 2 * FFI * HID * 2;
  u16* w2s_b   = (u16*)p;   p += (size_t)NEXP * HID * FFI * 2;

  u16* tb      = xn;                       // alias: xn dead after QKV GEMM
  float* oacc0 = qkvf;                     // alias: qkvf dead after k_sum2_bf16
  float* oacc1 = qkvf + (size_t)SEQ * HID;

  hipMemsetAsync(counts, 0, 32, stream);
  hipMemsetAsync(out0, 0, (size_t)SEQ * HID * 4, stream);

  k_f2b_small<<<(CN_SMALL / 4 + 255) / 256, 256, 0, stream>>>(
      wqkv, wo, wqkv_b, wo_b);
  k_rmsnorm<<<SEQ, 256, 0, stream>>>(hs, ln1, xn);
  // QKV: M=2048, N=1536, K=1024, split-K x2
  k_gemm_bt_sk<<<dim3(QKVD / 128, SEQ / 128, 2), 256, 0, stream>>>(
      xn, wqkv_b, qkvf, QKVD, HID, 512);
  k_sum2_bf16<<<(SEQ * QKVD / 4 + 255) / 256, 256, 0, stream>>>(
      qkvf, qkvf + (size_t)SEQ * QKVD, qkv, SEQ * QKVD / 4);
  // attention + fused ws/w2s conversion
  k_attn_conv<<<NATTN_BLK + NCONV_BLK, 256, 0, stream>>>(
      qkv, ob, wsx, w2s, ws_b, w2s_b);
  // O-proj: M=2048, N=1024, K=1024, split-K x2 (sum fused into rms2_router)
  k_gemm_bt_sk<<<dim3(HID / 128, SEQ / 128, 2), 256, 0, stream>>>(
      ob, wo_b, oacc0, HID, HID, 512);
  k_rms2_router<<<SEQ, 256, 0, stream>>>(oacc0, oacc1, hs, ln2, rwt, out1, tb,
                                         counts, tok_idx, tok_w);
  k_offsets<<<1, 64, 0, stream>>>(counts, offs);
  k_moe_gu<<<dim3(FFI / 64, SEQ / 128, NEXP), 256, 0, stream>>>(
      tb, ws_b, counts, offs, tok_idx, abuf);
  k_moe_y<<<dim3(HID / 128, SEQ / 128, NEXP * 4), 256, 0, stream>>>(
      abuf, w2s_b, counts, offs, tok_idx, tok_w, out0);
}